// Round 1
// 382.627 us; speedup vs baseline: 1.0747x; 1.0747x over previous
//
#include <hip/hip_runtime.h>

#define NS    23      // columns per row (dose + 22 masks)
#define NSTR  22      // structures
#define NPAIR 11      // structure pairs packed 2x16-bit
#define ND    85      // dose bins in the loss
#define NB    256     // histogram bins
#define H     0.4f    // bin width (covers [0, 102.4))
#define INV_H 2.5f
#define EPSF  1.1920929e-07f
#define BLK   512
#define MAXB  768     // 3 blocks/CU x 256 CUs (24 waves/CU)
#define TILE_F4 (BLK * NS / 4)   // 2944 float4 per tile
#define ROWSTEP (4 * BLK / NS)   // 89 rows per k-slot advance
// NOTE: 4*BLK % NS == 1 for BLK=512 -> col advances by exactly 1 per k-slot.

// ---------------- Pass 1: bit-compressed tiles + packed dual histograms -----
// Rationale (R3): counters showed latency-bound (HBM 15%, VALU 13%, occ 32%).
//  - loader threads compress each row to 1 u32 of mask bits + 1 dose float
//    (LDS tile 23.5KB -> 4KB, double-buffered; 1 LDS read/row in process)
//  - loads for tile t+1 issued right after the barrier -> in flight across
//    processing; next convert consumes them so syncthreads' vmcnt drain is free
//  - two UNSIGNED histograms (+1@qt into ht, +1@qp into hp), 16-bit packed
//    pairs (s, s+11): per-block counts <= 3072 << 65536 (needs rounds <= 127;
//    holds for any N <= ~16.7e9 rows). cnt[s] = sum_q ht[s][q], free in pass 2.
__global__ __launch_bounds__(BLK, 6) void dvh_hist_kernel(
    const float* __restrict__ yt,   // y_true f32, N x 23
    const float* __restrict__ yp,   // y_pred f32, N x 23 (only col 0 used)
    int N, int numTiles,
    unsigned int* __restrict__ g_ht,   // NB x NPAIR packed
    unsigned int* __restrict__ g_hp)   // NB x NPAIR packed
{
    __shared__ unsigned int s_ht[NB * NPAIR];    // 11264 B
    __shared__ unsigned int s_hp[NB * NPAIR];    // 11264 B
    __shared__ unsigned int s_bits[2][BLK];      // 4096 B
    __shared__ float        s_dose[2][BLK];      // 4096 B -> 30720 B total

    const int tid = threadIdx.x;

    for (int i = tid; i < NB * NPAIR; i += BLK) { s_ht[i] = 0u; s_hp[i] = 0u; }
    s_bits[0][tid] = 0u; s_bits[1][tid] = 0u;

    const size_t totalF = (size_t)N * NS;
    const float4* __restrict__ yt4 = (const float4*)yt;

    // per-thread slot geometry: flat float base of slot k is 4*(tid + BLK*k);
    // row/col advance per k: row += 89 (+1 on col wrap), col += 1.
    int r_base = (4 * tid) / NS;
    int c_base = (4 * tid) - NS * r_base;
    const bool k5_valid = (tid + BLK * 5) < TILE_F4;   // tid < 384

    __syncthreads();

    size_t tile = blockIdx.x;
    const int stride = gridDim.x;

    float4 v[6];
    float pcur = 0.f, pnext = 0.f;

    // ---- prologue: issue tile-0 loads ----
    if (tile < (size_t)numTiles) {
        size_t b4 = tile * TILE_F4;
#pragma unroll
        for (int k = 0; k < 6; ++k) {
            int idx4 = tid + BLK * k;
            float4 t = make_float4(0.f, 0.f, 0.f, 0.f);
            if ((k < 5) || k5_valid) {
                size_t g4 = b4 + (size_t)idx4;
                size_t f = g4 << 2;
                if (f + 4 <= totalF) t = yt4[g4];
                else {
                    if (f     < totalF) t.x = yt[f];
                    if (f + 1 < totalF) t.y = yt[f + 1];
                    if (f + 2 < totalF) t.z = yt[f + 2];
                    if (f + 3 < totalF) t.w = yt[f + 3];
                }
            }
            v[k] = t;
        }
        size_t n = tile * BLK + tid;
        pcur = (n < (size_t)N) ? yp[n * NS] : 0.f;
    }

    int p = 0;
    for (; tile < (size_t)numTiles; tile += stride) {
        size_t nxt = tile + stride;

        // ---- 1) convert v -> buf[p] (waits on loads issued last round) ----
        {
            int r = r_base, c = c_base;
#pragma unroll
            for (int k = 0; k < 6; ++k) {
                if ((k < 5) || k5_valid) {
                    float4 t = v[k];
                    unsigned int oA = 0u, oB = 0u;
#pragma unroll
                    for (int j = 0; j < 4; ++j) {
                        float x = (j == 0) ? t.x : (j == 1) ? t.y : (j == 2) ? t.z : t.w;
                        int col = c + j;
                        int wr  = (col >= NS) ? 1 : 0;
                        int cc  = col - NS * wr;
                        if (cc == 0) {
                            s_dose[p][r + wr] = x;          // unique writer per row
                        } else {
                            unsigned int bb = (x != 0.f) ? (1u << (cc - 1)) : 0u;
                            if (wr) oB |= bb; else oA |= bb;
                        }
                    }
                    if (oA) atomicOr(&s_bits[p][r], oA);
                    if (oB) atomicOr(&s_bits[p][r + 1], oB);
                }
                c += 1; r += ROWSTEP;
                if (c >= NS) { c -= NS; r += 1; }
            }
        }

        __syncthreads();   // vmcnt naturally ~0 here (convert consumed v)

        // ---- 2) issue loads for next tile (in flight during processing) ----
        if (nxt < (size_t)numTiles) {
            size_t b4 = nxt * TILE_F4;
#pragma unroll
            for (int k = 0; k < 6; ++k) {
                int idx4 = tid + BLK * k;
                float4 t = make_float4(0.f, 0.f, 0.f, 0.f);
                if ((k < 5) || k5_valid) {
                    size_t g4 = b4 + (size_t)idx4;
                    size_t f = g4 << 2;
                    if (f + 4 <= totalF) t = yt4[g4];
                    else {
                        if (f     < totalF) t.x = yt[f];
                        if (f + 1 < totalF) t.y = yt[f + 1];
                        if (f + 2 < totalF) t.z = yt[f + 2];
                        if (f + 3 < totalF) t.w = yt[f + 3];
                    }
                }
                v[k] = t;
            }
            size_t n = nxt * BLK + tid;
            pnext = (n < (size_t)N) ? yp[n * NS] : 0.f;
        }

        // ---- 3) process row tid of buf[p] ----
        {
            unsigned int bits = s_bits[p][tid];
            s_bits[p][tid] = 0u;                 // safe: reused 2 rounds later
            float t0 = s_dose[p][tid];
            if (bits) {
                int qt = (int)(t0 * INV_H);
                qt = qt > 0 ? qt : 0;
                qt = qt < NB - 1 ? qt : NB - 1;
                float pr = fmaxf(pcur, 0.f);
                int qp = (int)(pr * INV_H);
                qp = qp < NB - 1 ? qp : NB - 1;
                unsigned int* ht = &s_ht[qt * NPAIR];
                unsigned int* hp = &s_hp[qp * NPAIR];
                unsigned int pb = (bits | (bits >> NPAIR)) & 0x7FFu;
                while (pb) {                      // avg ~3 iters
                    int w = __builtin_ctz(pb); pb &= pb - 1u;
                    unsigned int add = ((bits >> w) & 1u)
                                     | (((bits >> (w + NPAIR)) & 1u) << 16);
                    atomicAdd(ht + w, add);
                    atomicAdd(hp + w, add);
                }
            }
            pcur = pnext;
            p ^= 1;
        }
    }

    // ---- flush packed block-local histograms ----
    __syncthreads();
    for (int i = tid; i < NB * NPAIR; i += BLK) {
        unsigned int a = s_ht[i]; if (a) atomicAdd(&g_ht[i], a);
        unsigned int b = s_hp[i]; if (b) atomicAdd(&g_hp[i], b);
    }
}

// ---------------- Pass 2: decode packed hists, sigmoid-weighted reduce ------
__global__ void dvh_reduce_kernel(const unsigned int* __restrict__ g_ht,
                                  const unsigned int* __restrict__ g_hp,
                                  float* __restrict__ dsq)   // ND x NSTR
{
    int d = blockIdx.x;        // 0..84
    int lane = threadIdx.x;    // 0..63

    float at[NSTR], ap[NSTR], cn[NSTR];
#pragma unroll
    for (int s = 0; s < NSTR; ++s) { at[s] = 0.f; ap[s] = 0.f; cn[s] = 0.f; }

#pragma unroll
    for (int j = 0; j < NB / 64; ++j) {
        int q = lane + 64 * j;
        float c = ((float)q + 0.5f) * H;
        float wgt = 1.0f / (1.0f + __expf((float)d - c));   // sigmoid(c - d)
#pragma unroll
        for (int w = 0; w < NPAIR; ++w) {
            unsigned int t  = g_ht[q * NPAIR + w];
            unsigned int pk = g_hp[q * NPAIR + w];
            float tlo = (float)(t & 0xFFFFu),  thi = (float)(t >> 16);
            float plo = (float)(pk & 0xFFFFu), phi = (float)(pk >> 16);
            at[w]         += wgt * tlo;  at[w + NPAIR] += wgt * thi;
            ap[w]         += wgt * plo;  ap[w + NPAIR] += wgt * phi;
            cn[w]         += tlo;        cn[w + NPAIR] += thi;
        }
    }

#pragma unroll
    for (int s = 0; s < NSTR; ++s) {
#pragma unroll
        for (int o = 32; o; o >>= 1) {
            at[s] += __shfl_xor(at[s], o);
            ap[s] += __shfl_xor(ap[s], o);
            cn[s] += __shfl_xor(cn[s], o);
        }
    }

    if (lane == 0) {
#pragma unroll
        for (int s = 0; s < NSTR; ++s) {
            float diff = (at[s] - ap[s]) / (cn[s] + EPSF);
            dsq[d * NSTR + s] = diff * diff;
        }
    }
}

// ------- Pass 3: per-structure L2 over d, sum, scale (unchanged) ------------
__global__ void dvh_final_kernel(const float* __restrict__ dsq,
                                 float* __restrict__ out)
{
    int s = threadIdx.x;   // 0..63
    float r = 0.0f;
    if (s < NSTR) {
        float a = 0.0f;
        for (int d = 0; d < ND; ++d) a += dsq[d * NSTR + s];
        r = sqrtf(a);
    }
#pragma unroll
    for (int o = 32; o; o >>= 1) r += __shfl_xor(r, o);
    if (s == 0) out[0] = r / (float)(ND * NSTR);
}

extern "C" void kernel_launch(void* const* d_in, const int* in_sizes, int n_in,
                              void* d_out, int out_size, void* d_ws, size_t ws_size,
                              hipStream_t stream) {
    const float* yt = (const float*)d_in[0];
    const float* yp = (const float*)d_in[1];
    int N = in_sizes[0] / NS;

    unsigned int* g_ht = (unsigned int*)d_ws;                       // 11264 B
    unsigned int* g_hp = g_ht + NB * NPAIR;                         // 11264 B
    float* dsq = (float*)((char*)d_ws + 2 * NB * NPAIR * 4 + 128);  // 85*22*4 B

    hipMemsetAsync(d_ws, 0, 2 * NB * NPAIR * 4, stream);

    int numTiles = (N + BLK - 1) / BLK;
    int grid = numTiles < MAXB ? numTiles : MAXB;

    dvh_hist_kernel<<<grid, BLK, 0, stream>>>(yt, yp, N, numTiles, g_ht, g_hp);
    dvh_reduce_kernel<<<ND, 64, 0, stream>>>(g_ht, g_hp, dsq);
    dvh_final_kernel<<<1, 64, 0, stream>>>(dsq, (float*)d_out);
}